// Round 6
// baseline (172.234 us; speedup 1.0000x reference)
//
#include <hip/hip_runtime.h>

#define BB   1024
#define TT   512
#define NIN  28
#define NOUT 28
#define NS   4
#define MM   7
#define WW   457          // TT - NIN - NOUT + 1
#define SLEN 519          // MM + 1 + TT - 1
#define EMB  9            // 1 + 1 + MM

#define OUT1_SZ (WW * BB * 144)
#define OUT2_SZ (WW * BB * 28)
#define OUT3_SZ (BB * TT)
#define OUT4_SZ (BB * SLEN)

#define CH   32
#define NCH  (TT / CH)    // 16

typedef float f4 __attribute__((ext_vector_type(4)));

__device__ __forceinline__ f4 ld4u(const float* p) {   // 4B-aligned 16B load
    f4 v;
    __builtin_memcpy(&v, p, sizeof(f4));
    return v;
}

// ---------------------------------------------------------------------------
// Kernel 1: ES scan. 16 blocks x 64 threads; global->reg prefetch dbuf;
// LDS staging for coalesced global I/O. (~10-15 us)
// ---------------------------------------------------------------------------
__global__ __launch_bounds__(64) void es_scan(const float* __restrict__ Y,
        const int* __restrict__ idxs, const float* __restrict__ EW,
        float* __restrict__ levels, float* __restrict__ seas) {
    __shared__ float yl[64][CH + 1];
    __shared__ float se[64][CH + 1];
    const int tid = threadIdx.x;
    const int b0  = blockIdx.x << 6;
    const int b   = b0 + tid;

    const float* e = EW + idxs[b] * EMB;
    const float lev_sms  = 1.0f / (1.0f + __expf(-e[0]));
    const float seas_sms = 1.0f / (1.0f + __expf(-e[1]));
    const float a_l = 1.0f - lev_sms;
    const float a_s = 1.0f - seas_sms;

    float buf[MM];
    const float is0 = __expf(e[2]);
    {
        float* srow = seas + b * SLEN;
        srow[0] = is0;
#pragma unroll
        for (int k = 1; k < MM; ++k) {
            float v = __expf(e[2 + k]);
            srow[k] = v;
            buf[k - 1] = v;
        }
        buf[MM - 1] = is0;
    }

    f4 pf[8];
#pragma unroll
    for (int k = 0; k < 8; ++k) {
        int flat = (k << 6) + tid;
        int r = flat >> 3, q = flat & 7;
        pf[k] = *reinterpret_cast<const f4*>(Y + (b0 + r) * TT + (q << 2));
    }

    float lev = 0.0f;

#define ES_STEP(TTI)                                                        \
    {                                                                       \
        float y  = yreg[TTI];                                               \
        float st = buf[0];                                                  \
        lev = lev_sms * __fdividef(y, st) + a_l * lev;                      \
        float ns = seas_sms * __fdividef(y, lev) + a_s * st;                \
        buf[0] = buf[1]; buf[1] = buf[2]; buf[2] = buf[3];                  \
        buf[3] = buf[4]; buf[4] = buf[5]; buf[5] = buf[6];                  \
        buf[6] = ns;                                                        \
        yl[tid][TTI] = lev;                                                 \
        se[tid][TTI] = ns;                                                  \
    }

    for (int c = 0; c < NCH; ++c) {
        __syncthreads();
#pragma unroll
        for (int k = 0; k < 8; ++k) {
            int flat = (k << 6) + tid;
            int r = flat >> 3, q = flat & 7;
            float* dst = &yl[r][q << 2];
            dst[0] = pf[k].x; dst[1] = pf[k].y; dst[2] = pf[k].z; dst[3] = pf[k].w;
        }
        __syncthreads();
        if (c < NCH - 1) {
#pragma unroll
            for (int k = 0; k < 8; ++k) {
                int flat = (k << 6) + tid;
                int r = flat >> 3, q = flat & 7;
                pf[k] = *reinterpret_cast<const f4*>(
                    Y + (b0 + r) * TT + (c + 1) * CH + (q << 2));
            }
        }

        float yreg[CH];
#pragma unroll
        for (int tt = 0; tt < CH; ++tt) yreg[tt] = yl[tid][tt];

        if (c == 0) {
            lev = __fdividef(yreg[0], is0);
            yl[tid][0] = lev;
            se[tid][0] = is0;
#pragma unroll
            for (int tt = 1; tt < CH; ++tt) ES_STEP(tt)
        } else {
#pragma unroll
            for (int tt = 0; tt < CH; ++tt) ES_STEP(tt)
        }
        __syncthreads();

#pragma unroll
        for (int k = 0; k < CH; ++k) {
            int flat = (k << 6) + tid;
            int r    = flat >> 5;
            int col  = flat & 31;
            levels[(b0 + r) * TT   + c * CH + col]      = yl[r][col];
            seas  [(b0 + r) * SLEN + MM + c * CH + col] = se[r][col];
        }
    }
#undef ES_STEP
}

// ---------------------------------------------------------------------------
// Kernel 2: streaming pass, FLAT DENSE mapping — i IS the output f4 index.
// Every wave writes 64 consecutive f4 (1KB dense); the grid walks the
// output arrays linearly. Plain stores. Divergent col-class branch is
// issue-bound ~17us chip-wide (acceptable; store stream density wins).
//   range 1: out1 f4 [0, WW*BB*36)   col 0..6 log | 7..20 Xc0 | 21..34 Xc1 | 35 S
//   range 2: out2/out5 f4 [0, WW*BB*7)
// ---------------------------------------------------------------------------
#define NF1  (WW * BB * 36)           // 16,846,848
#define NF2  (WW * BB * 7)            //  3,275,776
#define NTOT (NF1 + NF2)

__global__ __launch_bounds__(256) void main_stream(const float* __restrict__ S,
        const float* __restrict__ Y, const float* __restrict__ X,
        const float* __restrict__ mask, const float* __restrict__ levels,
        const float* __restrict__ seas, f4* __restrict__ out1,
        f4* __restrict__ out2, f4* __restrict__ out5) {
    int i = blockIdx.x * blockDim.x + threadIdx.x;
    const int stride = gridDim.x * blockDim.x;
    for (; i < NTOT; i += stride) {
        if (i < NF1) {
            int wb  = i / 36;
            int col = i - wb * 36;                // 0..35
            int b   = wb & (BB - 1);
            int w   = wb >> 10;
            f4 v;
            if (col < 7) {                        // log insample
                int base = w + (col << 2);
                float le = levels[b * TT + w + NIN - 1];
                f4 yv = ld4u(Y    + b * TT   + base);
                f4 sv = ld4u(seas + b * SLEN + base);
                v.x = __logf(__fdividef(yv.x, le * sv.x));
                v.y = __logf(__fdividef(yv.y, le * sv.y));
                v.z = __logf(__fdividef(yv.z, le * sv.z));
                v.w = __logf(__fdividef(yv.w, le * sv.w));
            } else if (col < 21) {                // X chan0, offsets w+0..55
                v = ld4u(X + (b * 2) * TT + w + ((col - 7) << 2));
            } else if (col < 35) {                // X chan1
                v = ld4u(X + (b * 2 + 1) * TT + w + ((col - 21) << 2));
            } else {                              // statics
                v = *reinterpret_cast<const f4*>(S + b * NS);
            }
            out1[i] = v;
        } else {
            int k  = i - NF1;
            int wb = k / 7;
            int j  = k - wb * 7;                  // 0..6
            int b  = wb & (BB - 1);
            int w  = wb >> 10;
            int base = w + NIN + (j << 2);
            f4 vy = ld4u(Y    + b * TT + base);
            f4 vm = ld4u(mask + b * TT + base);
            out2[k] = vy;
            out5[k] = vm;
        }
    }
}

extern "C" void kernel_launch(void* const* d_in, const int* in_sizes, int n_in,
                              void* d_out, int out_size, void* d_ws, size_t ws_size,
                              hipStream_t stream) {
    const float* S    = (const float*)d_in[0];
    const float* Y    = (const float*)d_in[1];
    const float* X    = (const float*)d_in[2];
    const int*   idxs = (const int*)d_in[3];
    const float* mask = (const float*)d_in[4];
    const float* EW   = (const float*)d_in[5];

    float* out  = (float*)d_out;
    float* out1 = out;
    float* out2 = out1 + OUT1_SZ;
    float* out3 = out2 + OUT2_SZ;        // levels
    float* out4 = out3 + OUT3_SZ;        // seasonalities
    float* out5 = out4 + OUT4_SZ;        // mask_w

    es_scan<<<16, 64, 0, stream>>>(Y, idxs, EW, out3, out4);
    main_stream<<<2048, 256, 0, stream>>>(S, Y, X, mask, out3, out4,
                                          (f4*)out1, (f4*)out2, (f4*)out5);
}

// Round 7
// 159.499 us; speedup vs baseline: 1.0798x; 1.0798x over previous
//
#include <hip/hip_runtime.h>

#define BB   1024
#define TT   512
#define NIN  28
#define NOUT 28
#define NS   4
#define MM   7
#define WW   457          // TT - NIN - NOUT + 1
#define SLEN 519          // MM + 1 + TT - 1
#define EMB  9            // 1 + 1 + MM

#define OUT1_SZ (WW * BB * 144)
#define OUT2_SZ (WW * BB * 28)
#define OUT3_SZ (BB * TT)
#define OUT4_SZ (BB * SLEN)

#define CH   32
#define NCH  (TT / CH)    // 16

typedef float f4 __attribute__((ext_vector_type(4)));

__device__ __forceinline__ f4 ld4u(const float* p) {   // 4B-aligned 16B load
    f4 v;
    __builtin_memcpy(&v, p, sizeof(f4));
    return v;
}

// ---------------------------------------------------------------------------
// Kernel 1: ES scan. 16 blocks x 64 threads; global->reg prefetch dbuf;
// LDS staging for coalesced global I/O. (~10 us)  [unchanged from R4]
// ---------------------------------------------------------------------------
__global__ __launch_bounds__(64) void es_scan(const float* __restrict__ Y,
        const int* __restrict__ idxs, const float* __restrict__ EW,
        float* __restrict__ levels, float* __restrict__ seas) {
    __shared__ float yl[64][CH + 1];
    __shared__ float se[64][CH + 1];
    const int tid = threadIdx.x;
    const int b0  = blockIdx.x << 6;
    const int b   = b0 + tid;

    const float* e = EW + idxs[b] * EMB;
    const float lev_sms  = 1.0f / (1.0f + __expf(-e[0]));
    const float seas_sms = 1.0f / (1.0f + __expf(-e[1]));
    const float a_l = 1.0f - lev_sms;
    const float a_s = 1.0f - seas_sms;

    float buf[MM];
    const float is0 = __expf(e[2]);
    {
        float* srow = seas + b * SLEN;
        srow[0] = is0;
#pragma unroll
        for (int k = 1; k < MM; ++k) {
            float v = __expf(e[2 + k]);
            srow[k] = v;
            buf[k - 1] = v;
        }
        buf[MM - 1] = is0;
    }

    f4 pf[8];
#pragma unroll
    for (int k = 0; k < 8; ++k) {
        int flat = (k << 6) + tid;
        int r = flat >> 3, q = flat & 7;
        pf[k] = *reinterpret_cast<const f4*>(Y + (b0 + r) * TT + (q << 2));
    }

    float lev = 0.0f;

#define ES_STEP(TTI)                                                        \
    {                                                                       \
        float y  = yreg[TTI];                                               \
        float st = buf[0];                                                  \
        lev = lev_sms * __fdividef(y, st) + a_l * lev;                      \
        float ns = seas_sms * __fdividef(y, lev) + a_s * st;                \
        buf[0] = buf[1]; buf[1] = buf[2]; buf[2] = buf[3];                  \
        buf[3] = buf[4]; buf[4] = buf[5]; buf[5] = buf[6];                  \
        buf[6] = ns;                                                        \
        yl[tid][TTI] = lev;                                                 \
        se[tid][TTI] = ns;                                                  \
    }

    for (int c = 0; c < NCH; ++c) {
        __syncthreads();
#pragma unroll
        for (int k = 0; k < 8; ++k) {
            int flat = (k << 6) + tid;
            int r = flat >> 3, q = flat & 7;
            float* dst = &yl[r][q << 2];
            dst[0] = pf[k].x; dst[1] = pf[k].y; dst[2] = pf[k].z; dst[3] = pf[k].w;
        }
        __syncthreads();
        if (c < NCH - 1) {
#pragma unroll
            for (int k = 0; k < 8; ++k) {
                int flat = (k << 6) + tid;
                int r = flat >> 3, q = flat & 7;
                pf[k] = *reinterpret_cast<const f4*>(
                    Y + (b0 + r) * TT + (c + 1) * CH + (q << 2));
            }
        }

        float yreg[CH];
#pragma unroll
        for (int tt = 0; tt < CH; ++tt) yreg[tt] = yl[tid][tt];

        if (c == 0) {
            lev = __fdividef(yreg[0], is0);
            yl[tid][0] = lev;
            se[tid][0] = is0;
#pragma unroll
            for (int tt = 1; tt < CH; ++tt) ES_STEP(tt)
        } else {
#pragma unroll
            for (int tt = 0; tt < CH; ++tt) ES_STEP(tt)
        }
        __syncthreads();

#pragma unroll
        for (int k = 0; k < CH; ++k) {
            int flat = (k << 6) + tid;
            int r    = flat >> 5;
            int col  = flat & 31;
            levels[(b0 + r) * TT   + c * CH + col]      = yl[r][col];
            seas  [(b0 + r) * SLEN + MM + c * CH + col] = se[r][col];
        }
    }
#undef ES_STEP
}

// ---------------------------------------------------------------------------
// Kernel 2: LDS-staged streaming. Block = 2 consecutive batch rows x all w.
// Each input byte is read from global EXACTLY ONCE chip-wide (~12 MB/replay);
// all 28x window reuse served from LDS. Plain stores -> full L2 write-back
// line merging (every out1 chunk = 18 full lines from one instruction).
// 512 blocks x 256 threads, 24.6 KB LDS, 2 blocks/CU.
// ---------------------------------------------------------------------------
#define NJ1 (WW * 72)    // out1 f4 per block (457 w * 2 b * 36 cols)
#define NJ2 (WW * 14)    // out2/out5 f4 per block (457 w * 2 b * 7 cols)

__global__ __launch_bounds__(256) void lds_stream(const float* __restrict__ S,
        const float* __restrict__ Y, const float* __restrict__ X,
        const float* __restrict__ mask, const float* __restrict__ levels,
        const float* __restrict__ seas, f4* __restrict__ out1,
        f4* __restrict__ out2, f4* __restrict__ out5) {
    __shared__ float X0[2][TT];
    __shared__ float X1[2][TT];
    __shared__ float Yl[2][TT];
    __shared__ float Ml[2][TT];
    __shared__ float LV[2][TT];
    __shared__ float SEg[2][TT];
    __shared__ float Sl[2][NS];

    const int tid = threadIdx.x;
    const int b0  = blockIdx.x << 1;

    // ---- stage: 6 arrays x 2 rows x 128 f4; one f4 per thread per array ----
    {
        int r = tid >> 7;                 // 0..1
        int q = (tid & 127) << 2;         // float offset 0..508
        int b = b0 + r;
        ((f4*)X0)[tid]  = *reinterpret_cast<const f4*>(X + (size_t)(b * 2    ) * TT + q);
        ((f4*)X1)[tid]  = *reinterpret_cast<const f4*>(X + (size_t)(b * 2 + 1) * TT + q);
        ((f4*)Yl)[tid]  = *reinterpret_cast<const f4*>(Y      + (size_t)b * TT + q);
        ((f4*)Ml)[tid]  = *reinterpret_cast<const f4*>(mask   + (size_t)b * TT + q);
        ((f4*)LV)[tid]  = *reinterpret_cast<const f4*>(levels + (size_t)b * TT + q);
        ((f4*)SEg)[tid] = ld4u(seas + (size_t)b * SLEN + q);   // 519-stride: unaligned
        if (tid < 8) Sl[tid >> 2][tid & 3] = S[(b0 + (tid >> 2)) * NS + (tid & 3)];
    }
    __syncthreads();

    // ---- out1: 457 w x (2 b x 36 cols) dense f4 stores ----
    for (int j = tid; j < NJ1; j += 256) {
        int w   = j / 72;
        int c   = j - w * 72;
        int bl  = (c >= 36) ? 1 : 0;
        int col = c - 36 * bl;
        f4 v;
        if (col < 7) {                        // log insample
            int idx  = w + (col << 2);
            float le = LV[bl][w + NIN - 1];
            v.x = __logf(__fdividef(Yl[bl][idx    ], le * SEg[bl][idx    ]));
            v.y = __logf(__fdividef(Yl[bl][idx + 1], le * SEg[bl][idx + 1]));
            v.z = __logf(__fdividef(Yl[bl][idx + 2], le * SEg[bl][idx + 2]));
            v.w = __logf(__fdividef(Yl[bl][idx + 3], le * SEg[bl][idx + 3]));
        } else if (col < 21) {                // X chan0, offsets w+0..55
            int ix = w + ((col - 7) << 2);
            v.x = X0[bl][ix]; v.y = X0[bl][ix + 1];
            v.z = X0[bl][ix + 2]; v.w = X0[bl][ix + 3];
        } else if (col < 35) {                // X chan1
            int ix = w + ((col - 21) << 2);
            v.x = X1[bl][ix]; v.y = X1[bl][ix + 1];
            v.z = X1[bl][ix + 2]; v.w = X1[bl][ix + 3];
        } else {                              // statics
            v.x = Sl[bl][0]; v.y = Sl[bl][1]; v.z = Sl[bl][2]; v.w = Sl[bl][3];
        }
        out1[((w << 10) + b0 + bl) * 36 + col] = v;
    }

    // ---- out2 + out5: 457 w x (2 b x 7 cols) ----
    for (int j = tid; j < NJ2; j += 256) {
        int w  = j / 14;
        int c  = j - w * 14;
        int bl = (c >= 7) ? 1 : 0;
        int jj = c - 7 * bl;
        int idx = w + NIN + (jj << 2);
        f4 vy, vm;
        vy.x = Yl[bl][idx]; vy.y = Yl[bl][idx + 1];
        vy.z = Yl[bl][idx + 2]; vy.w = Yl[bl][idx + 3];
        vm.x = Ml[bl][idx]; vm.y = Ml[bl][idx + 1];
        vm.z = Ml[bl][idx + 2]; vm.w = Ml[bl][idx + 3];
        int o = ((w << 10) + b0 + bl) * 7 + jj;
        out2[o] = vy;
        out5[o] = vm;
    }
}

extern "C" void kernel_launch(void* const* d_in, const int* in_sizes, int n_in,
                              void* d_out, int out_size, void* d_ws, size_t ws_size,
                              hipStream_t stream) {
    const float* S    = (const float*)d_in[0];
    const float* Y    = (const float*)d_in[1];
    const float* X    = (const float*)d_in[2];
    const int*   idxs = (const int*)d_in[3];
    const float* mask = (const float*)d_in[4];
    const float* EW   = (const float*)d_in[5];

    float* out  = (float*)d_out;
    float* out1 = out;
    float* out2 = out1 + OUT1_SZ;
    float* out3 = out2 + OUT2_SZ;        // levels
    float* out4 = out3 + OUT3_SZ;        // seasonalities
    float* out5 = out4 + OUT4_SZ;        // mask_w

    es_scan<<<16, 64, 0, stream>>>(Y, idxs, EW, out3, out4);
    lds_stream<<<BB / 2, 256, 0, stream>>>(S, Y, X, mask, out3, out4,
                                           (f4*)out1, (f4*)out2, (f4*)out5);
}